// Round 6
// baseline (509.273 us; speedup 1.0000x reference)
//
#include <hip/hip_runtime.h>

// MoE router (BaseRouter): B=2,S=2048,H=2048,E=8,K=2,cap_factor=1.5
#define HID   2048
#define NE    8
#define NK    2
#define NTOK  4096              // B*S
#define NASS  (NTOK * NK)       // 8192 assignments
#define CAP   1536              // int(T*1.5*K/E)
#define DISP_ELEMS ((size_t)NTOK * NE * CAP)   // 50331648 floats per tensor
#define KBLK  (HID / 32)        // 64 k-blocks of 32 fp32 elements
#define NXBLK (NTOK * KBLK)     // X k-block groups for split
#define ZCHUNKS_PER_BLK 49152   // (2*DISP_ELEMS/4) / 512 blocks, 16B chunks

typedef __bf16 bf16x8 __attribute__((ext_vector_type(8)));
typedef float  f32x4  __attribute__((ext_vector_type(4)));

typedef const __attribute__((address_space(1))) unsigned int GUint;
typedef       __attribute__((address_space(3))) unsigned int LUint;

__device__ __forceinline__ void gload16(const void* g, void* l) {
    __builtin_amdgcn_global_load_lds((GUint*)g, (LUint*)l, 16, 0, 0);
}

// ---------------------------------------------------------------------------
// K0: fp32 -> split bf16 hi/lo for BOTH X and W1 in one launch.
// Layout [row][KBLK][32hi|32lo] (128B per k-block).
// ---------------------------------------------------------------------------
__global__ __launch_bounds__(256) void split_kernel(
    const float* __restrict__ X, const float* __restrict__ W1,
    __bf16* __restrict__ Xs, __bf16* __restrict__ Ws)
{
    int g = blockIdx.x * 256 + threadIdx.x;           // one 8-element group
    int blk = g >> 2, sub = g & 3;
    const float* s;
    __bf16* d;
    if (blk < NXBLK) { s = X  + (size_t)blk * 32 + sub * 8;
                       d = Xs + (size_t)blk * 64; }
    else             { s = W1 + (size_t)(blk - NXBLK) * 32 + sub * 8;
                       d = Ws + (size_t)(blk - NXBLK) * 64; }
    float x[8];
    float4 v0 = ((const float4*)s)[0], v1 = ((const float4*)s)[1];
    x[0]=v0.x; x[1]=v0.y; x[2]=v0.z; x[3]=v0.w;
    x[4]=v1.x; x[5]=v1.y; x[6]=v1.z; x[7]=v1.w;
    bf16x8 h8, l8;
#pragma unroll
    for (int j = 0; j < 8; ++j) {
        __bf16 h = (__bf16)x[j];
        h8[j] = h;
        l8[j] = (__bf16)(x[j] - (float)h);
    }
    *(bf16x8*)(d + sub * 8)      = h8;
    *(bf16x8*)(d + 32 + sub * 8) = l8;
}

// ---------------------------------------------------------------------------
// K1: h = relu(X @ W1^T + b1) via bf16x3-split MFMA + fused zero-fill of
// dispatch+combine (402MB NT stores hidden under the MFMA loop).
// m97 structure: SINGLE 32KB LDS buffer, 2 barriers/K-step, 3 blocks/CU —
// cross-block wave overlap hides the vmcnt(0) barrier drain (m114), which
// the round-2 "dbuf" (64KB LDS, 2 blocks/CU, drain of just-issued loads)
// did not.
// ---------------------------------------------------------------------------
__global__ __launch_bounds__(256, 3) void gemm1_mfma_kernel(
    const __bf16* __restrict__ Xs,   // [4096][KBLK][64]
    const __bf16* __restrict__ Ws,   // [2048][KBLK][64]
    const float* __restrict__ b1, float* __restrict__ hout,
    float* __restrict__ zout)        // d_out: 2*DISP_ELEMS floats to zero
{
    __shared__ __bf16 As[128 * 64];
    __shared__ __bf16 Bs[128 * 64];

    const int tid  = threadIdx.x;
    const int wid  = tid >> 6;
    const int lane = tid & 63;

    // bijective XCD swizzle (512 blocks, 512%8==0)
    int wg  = blockIdx.x;
    int swz = (wg & 7) * 64 + (wg >> 3);
    const int bx = swz & 15;          // N panel (2048/128 = 16)
    const int by = swz >> 4;          // M panel (4096/128 = 32)
    const int brow = by * 128;
    const int bcol = bx * 128;

    const int srow   = lane >> 3;
    const int sslot  = lane & 7;

    const int wr = wid >> 1, wc = wid & 1;
    const int fr = lane & 15;
    const int fc = lane >> 4;

    // fused-zero destination (raw blockIdx slice; ordering irrelevant)
    f32x4* zdst = (f32x4*)zout + (size_t)blockIdx.x * ZCHUNKS_PER_BLK + tid;
    const f32x4 zz = (f32x4)0.f;

    f32x4 acc[4][4];
#pragma unroll
    for (int m = 0; m < 4; ++m)
#pragma unroll
        for (int n = 0; n < 4; ++n) acc[m][n] = (f32x4)0.f;

    for (int b = 0; b < KBLK; ++b) {
        // stage tile b into the single LDS buffer (8x gload16/thread)
#pragma unroll
        for (int i = 0; i < 4; ++i) {
            int ra = wid * 32 + i * 8 + srow;
            int ca = sslot ^ (ra & 7);
            gload16(Xs + ((size_t)(brow + ra) * KBLK + b) * 64 + ca * 8,
                    &As[(wid * 32 + i * 8) * 64]);
            int cb = sslot ^ (ra & 7);
            gload16(Ws + ((size_t)(bcol + ra) * KBLK + b) * 64 + cb * 8,
                    &Bs[(wid * 32 + i * 8) * 64]);
        }
        __syncthreads();              // drains gload_lds (and prev NT stores)

        // fused zero-fill AFTER the drain barrier: these 3 NT stores are
        // drained at the *next* barrier, overlapping the MFMA phase below.
        {
            f32x4* z = zdst + (size_t)b * 768;
            __builtin_nontemporal_store(zz, z);
            __builtin_nontemporal_store(zz, z + 256);
            __builtin_nontemporal_store(zz, z + 512);
        }

        // b-fragments resident (32 VGPR), a-fragments streamed per-m
        bf16x8 bh[4], bl[4];
#pragma unroll
        for (int n = 0; n < 4; ++n) {
            int rb = wc * 64 + n * 16 + fr;
            bh[n] = *(const bf16x8*)&Bs[rb * 64 + ((fc       ^ (rb & 7)) << 3)];
            bl[n] = *(const bf16x8*)&Bs[rb * 64 + (((4 + fc) ^ (rb & 7)) << 3)];
        }
#pragma unroll
        for (int m = 0; m < 4; ++m) {
            int ra = wr * 64 + m * 16 + fr;
            bf16x8 ah = *(const bf16x8*)&As[ra * 64 + ((fc       ^ (ra & 7)) << 3)];
            bf16x8 al = *(const bf16x8*)&As[ra * 64 + (((4 + fc) ^ (ra & 7)) << 3)];
#pragma unroll
            for (int n = 0; n < 4; ++n) {
                f32x4 c = acc[m][n];
                c = __builtin_amdgcn_mfma_f32_16x16x32_bf16(ah, bh[n], c, 0, 0, 0);
                c = __builtin_amdgcn_mfma_f32_16x16x32_bf16(al, bh[n], c, 0, 0, 0);
                c = __builtin_amdgcn_mfma_f32_16x16x32_bf16(ah, bl[n], c, 0, 0, 0);
                acc[m][n] = c;
            }
        }
        __syncthreads();              // protect LDS for next stage (WAR)
    }

    // epilogue: C/D frag layout (m89): col = lane&15, row = (lane>>4)*4 + reg
#pragma unroll
    for (int m = 0; m < 4; ++m) {
#pragma unroll
        for (int n = 0; n < 4; ++n) {
            int row = brow + wr * 64 + m * 16 + fc * 4;
            int col = bcol + wc * 64 + n * 16 + fr;
            float bias = b1[col];
#pragma unroll
            for (int j = 0; j < 4; ++j) {
                float v = acc[m][n][j] + bias;
                hout[(size_t)(row + j) * HID + col] = fmaxf(v, 0.f);
            }
        }
    }
}

// ---------------------------------------------------------------------------
// K2: wave-per-token router: coalesced float4 loads, butterfly shfl reduce,
// lane-0 softmax/top-2. w2 (64KB) stays L1/L2-resident.
// ---------------------------------------------------------------------------
__global__ __launch_bounds__(256) void router_kernel(
    const float* __restrict__ hbuf, const float* __restrict__ w2,
    const float* __restrict__ b2, float* __restrict__ probs_out,
    int* __restrict__ topk_e, float* __restrict__ topk_p)
{
    const int t    = (blockIdx.x * 256 + threadIdx.x) >> 6;
    const int lane = threadIdx.x & 63;
    const float* hrow = hbuf + (size_t)t * HID;

    float acc[NE];
#pragma unroll
    for (int e = 0; e < NE; ++e) acc[e] = 0.f;

#pragma unroll
    for (int j = 0; j < HID / (64 * 4); ++j) {
        const int o = (j * 64 + lane) * 4;
        float4 hv = *(const float4*)(hrow + o);
#pragma unroll
        for (int e = 0; e < NE; ++e) {
            float4 wv = *(const float4*)(w2 + e * HID + o);
            acc[e] += hv.x * wv.x + hv.y * wv.y + hv.z * wv.z + hv.w * wv.w;
        }
    }
#pragma unroll
    for (int m = 32; m > 0; m >>= 1)
#pragma unroll
        for (int e = 0; e < NE; ++e) acc[e] += __shfl_xor(acc[e], m);

    if (lane == 0) {
        float lg[NE];
        float mx = -1e30f;
#pragma unroll
        for (int e = 0; e < NE; ++e) { lg[e] = acc[e] + b2[e]; mx = fmaxf(mx, lg[e]); }
        float sum = 0.f;
#pragma unroll
        for (int e = 0; e < NE; ++e) { lg[e] = expf(lg[e] - mx); sum += lg[e]; }
        float inv = 1.f / sum;
        float p[NE];
#pragma unroll
        for (int e = 0; e < NE; ++e) { p[e] = lg[e] * inv; probs_out[t * NE + e] = p[e]; }
        // top-2, strict '>' keeps lowest index on ties (matches jax.lax.top_k)
        int e1 = 0;
#pragma unroll
        for (int e = 1; e < NE; ++e) if (p[e] > p[e1]) e1 = e;
        int e2 = -1;
#pragma unroll
        for (int e = 0; e < NE; ++e) if (e != e1 && (e2 < 0 || p[e] > p[e2])) e2 = e;
        float denom = p[e1] + p[e2] + 1e-8f;
        topk_e[t * NK + 0] = e1;
        topk_e[t * NK + 1] = e2;
        topk_p[t * NK + 0] = p[e1] / denom;
        topk_p[t * NK + 1] = p[e2] / denom;
    }
}

// ---------------------------------------------------------------------------
// K3: fused positions+scatter+aux. One 256-thread block.
// ---------------------------------------------------------------------------
__global__ __launch_bounds__(256) void finalize_kernel(
    const int* __restrict__ topk_e, const float* __restrict__ topk_p,
    const float* __restrict__ probs, float* __restrict__ dispatch,
    float* __restrict__ combine, float* __restrict__ aux_out)
{
    const int tid = threadIdx.x;
    __shared__ int   sc[256][NE];
    __shared__ float tot[NE];
    __shared__ float rps[256][NE];

    int cnt[NE];
#pragma unroll
    for (int e = 0; e < NE; ++e) cnt[e] = 0;
    const int base = tid * 32;
    int eloc[32];
    for (int i = 0; i < 32; ++i) { eloc[i] = topk_e[base + i]; cnt[eloc[i]]++; }
#pragma unroll
    for (int e = 0; e < NE; ++e) sc[tid][e] = cnt[e];
    __syncthreads();
    if (tid < NE) {                          // serial exclusive scan per expert
        int run = 0;
        for (int i = 0; i < 256; ++i) { int v = sc[i][tid]; sc[i][tid] = run; run += v; }
        tot[tid] = (float)run;
    }
    __syncthreads();
    int run[NE];
#pragma unroll
    for (int e = 0; e < NE; ++e) run[e] = sc[tid][e];
    for (int i = 0; i < 32; ++i) {
        const int a = base + i;
        const int e = eloc[i];
        const int p = run[e]++;
        if (p < CAP) {
            const int t = a >> 1;
            const size_t off = ((size_t)t * NE + e) * CAP + p;
            dispatch[off] = 1.0f;
            combine[off]  = topk_p[a];
        }
    }

    float ps[NE];
#pragma unroll
    for (int e = 0; e < NE; ++e) ps[e] = 0.f;
    for (int t = tid; t < NTOK; t += 256)
#pragma unroll
        for (int e = 0; e < NE; ++e) ps[e] += probs[t * NE + e];
#pragma unroll
    for (int e = 0; e < NE; ++e) rps[tid][e] = ps[e];
    __syncthreads();
    for (int s = 128; s > 0; s >>= 1) {
        if (tid < s) {
#pragma unroll
            for (int e = 0; e < NE; ++e) rps[tid][e] += rps[tid + s][e];
        }
        __syncthreads();
    }
    if (tid == 0) {
        float aux = 0.f;
#pragma unroll
        for (int e = 0; e < NE; ++e)
            aux += (rps[0][e] / (float)NTOK) * (tot[e] / (float)NASS);
        aux_out[0] = aux * (float)NE;
    }
}

// ---------------------------------------------------------------------------
extern "C" void kernel_launch(void* const* d_in, const int* in_sizes, int n_in,
                              void* d_out, int out_size, void* d_ws, size_t ws_size,
                              hipStream_t stream)
{
    const float* X  = (const float*)d_in[0];   // [2,2048,2048]
    const float* w1 = (const float*)d_in[1];   // [2048,2048]
    const float* b1 = (const float*)d_in[2];   // [2048]
    const float* w2 = (const float*)d_in[3];   // [8,2048]
    const float* b2 = (const float*)d_in[4];   // [8]

    float* out      = (float*)d_out;
    float* dispatch = out;                                   // [T,E,CAP]
    float* combine  = out + DISP_ELEMS;                      // [T,E,CAP]
    float* probs    = out + 2 * DISP_ELEMS;                  // [T,E]
    float* aux      = out + 2 * DISP_ELEMS + (size_t)NTOK * NE;

    // Scratch in d_ws (~84MB; ws arena is ~1.6GB per harness poison fills):
    __bf16* Xs     = (__bf16*)d_ws;                          // 33.5MB
    __bf16* Ws     = Xs + (size_t)NTOK * HID * 2;            // 16.8MB
    float*  hbuf   = (float*)(Ws + (size_t)HID * HID * 2);   // 33.5MB
    int*    topk_e = (int*)(hbuf + (size_t)NTOK * HID);      // 8192 ints
    float*  topk_p = (float*)(topk_e + NASS);                // 8192 floats

    split_kernel<<<((NTOK + HID) * KBLK * 4) / 256, 256, 0, stream>>>(X, w1, Xs, Ws);
    gemm1_mfma_kernel<<<512, 256, 0, stream>>>(Xs, Ws, b1, hbuf, out);
    router_kernel<<<NTOK / 4, 256, 0, stream>>>(hbuf, w2, b2, probs, topk_e, topk_p);
    finalize_kernel<<<1, 256, 0, stream>>>(topk_e, topk_p, probs, dispatch, combine, aux);
}

// Round 7
// 501.244 us; speedup vs baseline: 1.0160x; 1.0160x over previous
//
#include <hip/hip_runtime.h>

// MoE router (BaseRouter): B=2,S=2048,H=2048,E=8,K=2,cap_factor=1.5
#define HID   2048
#define NE    8
#define NK    2
#define NTOK  4096              // B*S
#define NASS  (NTOK * NK)       // 8192 assignments
#define CAP   1536              // int(T*1.5*K/E)
#define DISP_ELEMS ((size_t)NTOK * NE * CAP)   // 50331648 floats per tensor
#define KBLK  (HID / 32)        // 64 k-blocks of 32 fp32 elements
#define NXBLK (NTOK * KBLK)     // X k-block groups for split
#define NPANEL 16               // N col-panels (2048/128)
#define ZCHUNKS_PER_BLK 49152   // (2*DISP_ELEMS/4) / 512 blocks, 16B chunks

typedef __bf16 bf16x8 __attribute__((ext_vector_type(8)));
typedef float  f32x4  __attribute__((ext_vector_type(4)));

typedef const __attribute__((address_space(1))) unsigned int GUint;
typedef       __attribute__((address_space(3))) unsigned int LUint;

__device__ __forceinline__ void gload16(const void* g, void* l) {
    __builtin_amdgcn_global_load_lds((GUint*)g, (LUint*)l, 16, 0, 0);
}

// ---------------------------------------------------------------------------
// K0: fp32 -> split bf16 hi/lo for BOTH X and W1 in one launch.
// Layout [row][KBLK][32hi|32lo] (128B per k-block).
// ---------------------------------------------------------------------------
__global__ __launch_bounds__(256) void split_kernel(
    const float* __restrict__ X, const float* __restrict__ W1,
    __bf16* __restrict__ Xs, __bf16* __restrict__ Ws)
{
    int g = blockIdx.x * 256 + threadIdx.x;           // one 8-element group
    int blk = g >> 2, sub = g & 3;
    const float* s;
    __bf16* d;
    if (blk < NXBLK) { s = X  + (size_t)blk * 32 + sub * 8;
                       d = Xs + (size_t)blk * 64; }
    else             { s = W1 + (size_t)(blk - NXBLK) * 32 + sub * 8;
                       d = Ws + (size_t)(blk - NXBLK) * 64; }
    float x[8];
    float4 v0 = ((const float4*)s)[0], v1 = ((const float4*)s)[1];
    x[0]=v0.x; x[1]=v0.y; x[2]=v0.z; x[3]=v0.w;
    x[4]=v1.x; x[5]=v1.y; x[6]=v1.z; x[7]=v1.w;
    bf16x8 h8, l8;
#pragma unroll
    for (int j = 0; j < 8; ++j) {
        __bf16 h = (__bf16)x[j];
        h8[j] = h;
        l8[j] = (__bf16)(x[j] - (float)h);
    }
    *(bf16x8*)(d + sub * 8)      = h8;
    *(bf16x8*)(d + 32 + sub * 8) = l8;
}

// ---------------------------------------------------------------------------
// K1: bf16x3-split MFMA gemm for h = relu(X@W1^T+b1), FUSED with:
//  (a) zero-fill of dispatch+combine (402MB NT stores inside the K-loop)
//  (b) partial-logits epilogue: h never goes to HBM; instead each block
//      reduces its 128x128 h-tile against its 128 w2 columns and stores
//      partial[colpanel][token][e] (2MB, one writer per slot -> determinstic
//      fixed-order summation downstream; no atomics).
// ---------------------------------------------------------------------------
__global__ __launch_bounds__(256, 3) void gemm1_mfma_kernel(
    const __bf16* __restrict__ Xs,   // [4096][KBLK][64]
    const __bf16* __restrict__ Ws,   // [2048][KBLK][64]
    const float* __restrict__ b1,
    const float* __restrict__ w2,    // [8][2048]
    float* __restrict__ partial,     // [16][4096][8]
    float* __restrict__ zout)        // d_out: 2*DISP_ELEMS floats to zero
{
    __shared__ __bf16 As[128 * 64];
    __shared__ __bf16 Bs[128 * 64];
    __shared__ float  Part[2][64][2][NE];   // 8KB wc-combine slab

    const int tid  = threadIdx.x;
    const int wid  = tid >> 6;
    const int lane = tid & 63;

    // bijective XCD swizzle (512 blocks, 512%8==0)
    int wg  = blockIdx.x;
    int swz = (wg & 7) * 64 + (wg >> 3);
    const int bx = swz & 15;          // N panel (2048/128 = 16)
    const int by = swz >> 4;          // M panel (4096/128 = 32)
    const int brow = by * 128;
    const int bcol = bx * 128;

    const int srow   = lane >> 3;
    const int sslot  = lane & 7;

    const int wr = wid >> 1, wc = wid & 1;
    const int fr = lane & 15;
    const int fc = lane >> 4;

    f32x4* zdst = (f32x4*)zout + (size_t)blockIdx.x * ZCHUNKS_PER_BLK + tid;
    const f32x4 zz = (f32x4)0.f;

    f32x4 acc[4][4];
#pragma unroll
    for (int m = 0; m < 4; ++m)
#pragma unroll
        for (int n = 0; n < 4; ++n) acc[m][n] = (f32x4)0.f;

    for (int b = 0; b < KBLK; ++b) {
#pragma unroll
        for (int i = 0; i < 4; ++i) {
            int ra = wid * 32 + i * 8 + srow;
            int ca = sslot ^ (ra & 7);
            gload16(Xs + ((size_t)(brow + ra) * KBLK + b) * 64 + ca * 8,
                    &As[(wid * 32 + i * 8) * 64]);
            gload16(Ws + ((size_t)(bcol + ra) * KBLK + b) * 64 + ca * 8,
                    &Bs[(wid * 32 + i * 8) * 64]);
        }
        __syncthreads();              // drains gload_lds (and prev NT stores)

        // fused zero-fill, drained at the NEXT barrier (overlaps MFMA phase)
        {
            f32x4* z = zdst + (size_t)b * 768;
            __builtin_nontemporal_store(zz, z);
            __builtin_nontemporal_store(zz, z + 256);
            __builtin_nontemporal_store(zz, z + 512);
        }

        bf16x8 bh[4], bl[4];
#pragma unroll
        for (int n = 0; n < 4; ++n) {
            int rb = wc * 64 + n * 16 + fr;
            bh[n] = *(const bf16x8*)&Bs[rb * 64 + ((fc       ^ (rb & 7)) << 3)];
            bl[n] = *(const bf16x8*)&Bs[rb * 64 + (((4 + fc) ^ (rb & 7)) << 3)];
        }
#pragma unroll
        for (int m = 0; m < 4; ++m) {
            int ra = wr * 64 + m * 16 + fr;
            bf16x8 ah = *(const bf16x8*)&As[ra * 64 + ((fc       ^ (ra & 7)) << 3)];
            bf16x8 al = *(const bf16x8*)&As[ra * 64 + (((4 + fc) ^ (ra & 7)) << 3)];
#pragma unroll
            for (int n = 0; n < 4; ++n) {
                f32x4 c = acc[m][n];
                c = __builtin_amdgcn_mfma_f32_16x16x32_bf16(ah, bh[n], c, 0, 0, 0);
                c = __builtin_amdgcn_mfma_f32_16x16x32_bf16(al, bh[n], c, 0, 0, 0);
                c = __builtin_amdgcn_mfma_f32_16x16x32_bf16(ah, bl[n], c, 0, 0, 0);
                acc[m][n] = c;
            }
        }
        __syncthreads();              // protect LDS for next stage (WAR)
    }

    // ---- partial-logits epilogue ----
    // C/D frag layout (m89): col = bcol+wc*64+n*16+fr, row = brow+wr*64+m*16+fc*4+j
    float w2v[NE][4], bias4[4];
#pragma unroll
    for (int n = 0; n < 4; ++n) {
        int col = bcol + wc * 64 + n * 16 + fr;
        bias4[n] = b1[col];
#pragma unroll
        for (int e = 0; e < NE; ++e) w2v[e][n] = w2[e * HID + col];
    }
#pragma unroll
    for (int m = 0; m < 4; ++m) {
#pragma unroll
        for (int j = 0; j < 4; ++j) {
            float esum[NE];
#pragma unroll
            for (int e = 0; e < NE; ++e) esum[e] = 0.f;
#pragma unroll
            for (int n = 0; n < 4; ++n) {
                float h = fmaxf(acc[m][n][j] + bias4[n], 0.f);
#pragma unroll
                for (int e = 0; e < NE; ++e) esum[e] += h * w2v[e][n];
            }
            // tree-reduce across fr (16 lanes within each fc group)
#pragma unroll
            for (int msk = 1; msk < 16; msk <<= 1)
#pragma unroll
                for (int e = 0; e < NE; ++e) esum[e] += __shfl_xor(esum[e], msk);
            if (fr == 0) {
                int row64 = m * 16 + fc * 4 + j;
#pragma unroll
                for (int e = 0; e < NE; ++e) Part[wr][row64][wc][e] = esum[e];
            }
        }
    }
    __syncthreads();
    // combine wc halves in fixed order; one writer per output slot
#pragma unroll
    for (int it = 0; it < 4; ++it) {
        int idx = it * 256 + tid;               // 0..1023
        int row128 = idx >> 3, e = idx & 7;
        float v = Part[row128 >> 6][row128 & 63][0][e]
                + Part[row128 >> 6][row128 & 63][1][e];
        partial[((size_t)bx * NTOK + brow + row128) * NE + e] = v;
    }
}

// ---------------------------------------------------------------------------
// K2: logits = b2 + sum_panels(partial)  (fixed panel order -> deterministic),
// softmax, top-2. One thread per token; 16 blocks.
// ---------------------------------------------------------------------------
__global__ __launch_bounds__(256) void logits_topk_kernel(
    const float* __restrict__ partial, const float* __restrict__ b2,
    float* __restrict__ probs_out, int* __restrict__ topk_e,
    float* __restrict__ topk_p)
{
    const int t = blockIdx.x * 256 + threadIdx.x;   // 0..4095
    float lg[NE];
#pragma unroll
    for (int e = 0; e < NE; ++e) lg[e] = b2[e];
    for (int p = 0; p < NPANEL; ++p) {
        const float4* src = (const float4*)(partial + ((size_t)p * NTOK + t) * NE);
        float4 a = src[0], b = src[1];
        lg[0] += a.x; lg[1] += a.y; lg[2] += a.z; lg[3] += a.w;
        lg[4] += b.x; lg[5] += b.y; lg[6] += b.z; lg[7] += b.w;
    }
    float mx = -1e30f;
#pragma unroll
    for (int e = 0; e < NE; ++e) mx = fmaxf(mx, lg[e]);
    float sum = 0.f;
#pragma unroll
    for (int e = 0; e < NE; ++e) { lg[e] = expf(lg[e] - mx); sum += lg[e]; }
    float inv = 1.f / sum;
    float p[NE];
#pragma unroll
    for (int e = 0; e < NE; ++e) { p[e] = lg[e] * inv; probs_out[t * NE + e] = p[e]; }
    // top-2, strict '>' keeps lowest index on ties (matches jax.lax.top_k)
    int e1 = 0;
#pragma unroll
    for (int e = 1; e < NE; ++e) if (p[e] > p[e1]) e1 = e;
    int e2 = -1;
#pragma unroll
    for (int e = 0; e < NE; ++e) if (e != e1 && (e2 < 0 || p[e] > p[e2])) e2 = e;
    float denom = p[e1] + p[e2] + 1e-8f;
    topk_e[t * NK + 0] = e1;
    topk_e[t * NK + 1] = e2;
    topk_p[t * NK + 0] = p[e1] / denom;
    topk_p[t * NK + 1] = p[e2] / denom;
}

// ---------------------------------------------------------------------------
// K3: fused positions+scatter+aux. One 256-thread block.
// ---------------------------------------------------------------------------
__global__ __launch_bounds__(256) void finalize_kernel(
    const int* __restrict__ topk_e, const float* __restrict__ topk_p,
    const float* __restrict__ probs, float* __restrict__ dispatch,
    float* __restrict__ combine, float* __restrict__ aux_out)
{
    const int tid = threadIdx.x;
    __shared__ int   sc[256][NE];
    __shared__ float tot[NE];
    __shared__ float rps[256][NE];

    int cnt[NE];
#pragma unroll
    for (int e = 0; e < NE; ++e) cnt[e] = 0;
    const int base = tid * 32;
    int eloc[32];
    for (int i = 0; i < 32; ++i) { eloc[i] = topk_e[base + i]; cnt[eloc[i]]++; }
#pragma unroll
    for (int e = 0; e < NE; ++e) sc[tid][e] = cnt[e];
    __syncthreads();
    if (tid < NE) {                          // serial exclusive scan per expert
        int run = 0;
        for (int i = 0; i < 256; ++i) { int v = sc[i][tid]; sc[i][tid] = run; run += v; }
        tot[tid] = (float)run;
    }
    __syncthreads();
    int run[NE];
#pragma unroll
    for (int e = 0; e < NE; ++e) run[e] = sc[tid][e];
    for (int i = 0; i < 32; ++i) {
        const int a = base + i;
        const int e = eloc[i];
        const int p = run[e]++;
        if (p < CAP) {
            const int t = a >> 1;
            const size_t off = ((size_t)t * NE + e) * CAP + p;
            dispatch[off] = 1.0f;
            combine[off]  = topk_p[a];
        }
    }

    float ps[NE];
#pragma unroll
    for (int e = 0; e < NE; ++e) ps[e] = 0.f;
    for (int t = tid; t < NTOK; t += 256)
#pragma unroll
        for (int e = 0; e < NE; ++e) ps[e] += probs[t * NE + e];
#pragma unroll
    for (int e = 0; e < NE; ++e) rps[tid][e] = ps[e];
    __syncthreads();
    for (int s = 128; s > 0; s >>= 1) {
        if (tid < s) {
#pragma unroll
            for (int e = 0; e < NE; ++e) rps[tid][e] += rps[tid + s][e];
        }
        __syncthreads();
    }
    if (tid == 0) {
        float aux = 0.f;
#pragma unroll
        for (int e = 0; e < NE; ++e)
            aux += (rps[0][e] / (float)NTOK) * (tot[e] / (float)NASS);
        aux_out[0] = aux * (float)NE;
    }
}

// ---------------------------------------------------------------------------
extern "C" void kernel_launch(void* const* d_in, const int* in_sizes, int n_in,
                              void* d_out, int out_size, void* d_ws, size_t ws_size,
                              hipStream_t stream)
{
    const float* X  = (const float*)d_in[0];   // [2,2048,2048]
    const float* w1 = (const float*)d_in[1];   // [2048,2048]
    const float* b1 = (const float*)d_in[2];   // [2048]
    const float* w2 = (const float*)d_in[3];   // [8,2048]
    const float* b2 = (const float*)d_in[4];   // [8]

    float* out      = (float*)d_out;
    float* dispatch = out;                                   // [T,E,CAP]
    float* combine  = out + DISP_ELEMS;                      // [T,E,CAP]
    float* probs    = out + 2 * DISP_ELEMS;                  // [T,E]
    float* aux      = out + 2 * DISP_ELEMS + (size_t)NTOK * NE;

    // Scratch in d_ws (~53MB; ws arena is ~1.6GB per harness poison fills):
    __bf16* Xs      = (__bf16*)d_ws;                         // 33.5MB
    __bf16* Ws      = Xs + (size_t)NTOK * HID * 2;           // 16.8MB
    float*  partial = (float*)(Ws + (size_t)HID * HID * 2);  // 16*4096*8 = 2MB
    int*    topk_e  = (int*)(partial + (size_t)NPANEL * NTOK * NE);
    float*  topk_p  = (float*)(topk_e + NASS);

    split_kernel<<<((NTOK + HID) * KBLK * 4) / 256, 256, 0, stream>>>(X, w1, Xs, Ws);
    gemm1_mfma_kernel<<<512, 256, 0, stream>>>(Xs, Ws, b1, w2, partial, out);
    logits_topk_kernel<<<NTOK / 256, 256, 0, stream>>>(partial, b2, probs, topk_e, topk_p);
    finalize_kernel<<<1, 256, 0, stream>>>(topk_e, topk_p, probs, dispatch, combine, aux);
}